// Round 6
// baseline (353.832 us; speedup 1.0000x reference)
//
#include <hip/hip_runtime.h>

// Problem constants (fixed by the reference setup).
#define B_POSES  1048576
#define PERIOD   8
#define SEGS     (B_POSES / PERIOD)   // 131072 segments
#define C1       32                   // segments per chunk
#define NCHUNK   (SEGS / C1)          // 4096 chunks
#define SUP      16                   // chunks per super
#define NSUPER   (NCHUNK / SUP)       // 256 supers
#define HYP      16                   // supers per hyper
#define NHYPER   (NSUPER / HYP)       // 16 hypers

typedef float vfloat4 __attribute__((ext_vector_type(4)));  // clang-native, NT-store-able

// c = a @ b, row-major 4x4. c must not alias a/b.
__device__ __forceinline__ void mm4(const float* __restrict__ a,
                                    const float* __restrict__ b,
                                    float* __restrict__ c) {
#pragma unroll
    for (int i = 0; i < 4; ++i) {
#pragma unroll
        for (int j = 0; j < 4; ++j) {
            float s = a[i*4+0] * b[0*4+j];
            s = fmaf(a[i*4+1], b[1*4+j], s);
            s = fmaf(a[i*4+2], b[2*4+j], s);
            c[i*4+j] = fmaf(a[i*4+3], b[3*4+j], s);
        }
    }
}

__device__ __forceinline__ void load16(const float* __restrict__ p, float* __restrict__ d) {
    const vfloat4* v = reinterpret_cast<const vfloat4*>(p);
    vfloat4 v0 = v[0], v1 = v[1], v2 = v[2], v3 = v[3];
    d[0]=v0.x; d[1]=v0.y; d[2]=v0.z; d[3]=v0.w;
    d[4]=v1.x; d[5]=v1.y; d[6]=v1.z; d[7]=v1.w;
    d[8]=v2.x; d[9]=v2.y; d[10]=v2.z; d[11]=v2.w;
    d[12]=v3.x; d[13]=v3.y; d[14]=v3.z; d[15]=v3.w;
}

__device__ __forceinline__ void store16(float* __restrict__ p, const float* __restrict__ s) {
    vfloat4* v = reinterpret_cast<vfloat4*>(p);
    v[0] = (vfloat4){s[0], s[1], s[2], s[3]};
    v[1] = (vfloat4){s[4], s[5], s[6], s[7]};
    v[2] = (vfloat4){s[8], s[9], s[10], s[11]};
    v[3] = (vfloat4){s[12], s[13], s[14], s[15]};
}

__device__ __forceinline__ void store16_nt(float* __restrict__ p, const float* __restrict__ s) {
    vfloat4* v = reinterpret_cast<vfloat4*>(p);
    __builtin_nontemporal_store((vfloat4){s[0],  s[1],  s[2],  s[3]},  v + 0);
    __builtin_nontemporal_store((vfloat4){s[4],  s[5],  s[6],  s[7]},  v + 1);
    __builtin_nontemporal_store((vfloat4){s[8],  s[9],  s[10], s[11]}, v + 2);
    __builtin_nontemporal_store((vfloat4){s[12], s[13], s[14], s[15]}, v + 3);
}

// K1: chunkProd[c] = boundary[c*C1] @ ... @ boundary[c*C1+C1-1]
// Quad-row parallel: 4 lanes per chunk, one output row each. Each lane reads
// the full boundary matrix (quad lanes share the 64B cache line), updates only
// its row: row_new = row @ B. Same association order as a serial chain.
__global__ __launch_bounds__(256)
void k1_chunkprod(const float* __restrict__ E, float* __restrict__ chunkProd) {
    int tid = blockIdx.x * 256 + threadIdx.x;   // grid = NCHUNK*4 threads
    int c = tid >> 2;
    int r = tid & 3;
    const float* base = E + ((size_t)c * C1 * PERIOD + (PERIOD - 1)) * 16;
    vfloat4 rv = *reinterpret_cast<const vfloat4*>(base + r * 4);
    float row0 = rv.x, row1 = rv.y, row2 = rv.z, row3 = rv.w;
    float bm[16];
#pragma unroll 4
    for (int k = 1; k < C1; ++k) {
        load16(base + (size_t)k * PERIOD * 16, bm);
        float n0 = fmaf(row3, bm[12], fmaf(row2, bm[8],  fmaf(row1, bm[4], row0*bm[0])));
        float n1 = fmaf(row3, bm[13], fmaf(row2, bm[9],  fmaf(row1, bm[5], row0*bm[1])));
        float n2 = fmaf(row3, bm[14], fmaf(row2, bm[10], fmaf(row1, bm[6], row0*bm[2])));
        float n3 = fmaf(row3, bm[15], fmaf(row2, bm[11], fmaf(row1, bm[7], row0*bm[3])));
        row0 = n0; row1 = n1; row2 = n2; row3 = n3;
    }
    *reinterpret_cast<vfloat4*>(chunkProd + (size_t)c * 16 + r * 4) =
        (vfloat4){row0, row1, row2, row3};
}

// K2: hierarchical exclusive scan over the 4096 chunk products, kf0 folded in
// on the left. chunkPrefix[c] = kf0 @ prod(chunkProd[0..c-1]). Also emits lf.
__global__ __launch_bounds__(256)
void k2_scan(const float* __restrict__ kf, const float* __restrict__ chunkProd,
             float* __restrict__ chunkPrefix, float* __restrict__ lf_out) {
    __shared__ float sSup[NSUPER][16];      // super products
    __shared__ float sSupPref[NSUPER][16];  // kf0-folded prefix per super
    __shared__ float sHyp[NHYPER][16];
    __shared__ float sHypPref[NHYPER][16];
    int t = threadIdx.x;
    float run[16], bm[16], tmp[16];

    // Stage A: super products (all 256 threads, chain of 16)
    {
        const float* p = chunkProd + (size_t)t * SUP * 16;
        load16(p, run);
#pragma unroll 4
        for (int k = 1; k < SUP; ++k) {
            load16(p + (size_t)k * 16, bm);
            mm4(run, bm, tmp);
#pragma unroll
            for (int q = 0; q < 16; ++q) run[q] = tmp[q];
        }
#pragma unroll
        for (int q = 0; q < 16; ++q) sSup[t][q] = run[q];
    }
    __syncthreads();

    // Stage B1: hyper products (16 threads, chain of 16)
    if (t < NHYPER) {
#pragma unroll
        for (int q = 0; q < 16; ++q) run[q] = sSup[t*HYP][q];
        for (int k = 1; k < HYP; ++k) {
            mm4(run, sSup[t*HYP + k], tmp);
#pragma unroll
            for (int q = 0; q < 16; ++q) run[q] = tmp[q];
        }
#pragma unroll
        for (int q = 0; q < 16; ++q) sHyp[t][q] = run[q];
    }
    __syncthreads();

    // Stage B2: serial scan over 16 hypers (thread 0), kf0 at the left; and lf.
    if (t == 0) {
        load16(kf, run);
        for (int h = 0; h < NHYPER; ++h) {
#pragma unroll
            for (int q = 0; q < 16; ++q) sHypPref[h][q] = run[q];
            mm4(run, sHyp[h], tmp);
#pragma unroll
            for (int q = 0; q < 16; ++q) run[q] = tmp[q];
        }
        // lf = [[R^T, -R^T t],[kf0 row 3]]
        float lf[16];
#pragma unroll
        for (int i = 0; i < 3; ++i)
#pragma unroll
            for (int j = 0; j < 3; ++j)
                lf[i*4+j] = kf[j*4+i];
#pragma unroll
        for (int i = 0; i < 3; ++i)
            lf[i*4+3] = -(kf[0*4+i]*kf[0*4+3] + kf[1*4+i]*kf[1*4+3] + kf[2*4+i]*kf[2*4+3]);
        lf[12] = kf[12]; lf[13] = kf[13]; lf[14] = kf[14]; lf[15] = kf[15];
        store16(lf_out, lf);
    }
    __syncthreads();

    // Stage B3: prefix within each hyper (16 threads, chain of 16)
    if (t < NHYPER) {
#pragma unroll
        for (int q = 0; q < 16; ++q) run[q] = sHypPref[t][q];
        for (int k = 0; k < HYP; ++k) {
            int s = t*HYP + k;
#pragma unroll
            for (int q = 0; q < 16; ++q) sSupPref[s][q] = run[q];
            mm4(run, sSup[s], tmp);
#pragma unroll
            for (int q = 0; q < 16; ++q) run[q] = tmp[q];
        }
    }
    __syncthreads();

    // Stage C: prefix within each super (256 threads, chain of 16), to global ws
    {
#pragma unroll
        for (int q = 0; q < 16; ++q) run[q] = sSupPref[t][q];
        for (int k = 0; k < SUP; ++k) {
            int c = t*SUP + k;
            store16(chunkPrefix + (size_t)c * 16, run);
            load16(chunkProd + (size_t)c * 16, bm);
            mm4(run, bm, tmp);
#pragma unroll
            for (int q = 0; q < 16; ++q) run[q] = tmp[q];
        }
    }
}

// K3: one block per chunk (32 segments * 8 poses = 256 threads).
// Lanes 0-3 extend the chunk prefix across the 32 segments (row-parallel,
// no cross-thread deps), then every thread computes wf and lf_poses.
__global__ __launch_bounds__(256)
void k3_poses(const float* __restrict__ E, const float* __restrict__ chunkPrefix,
              const float* __restrict__ lf_in, float* __restrict__ out) {
    __shared__ float sB[C1][16];   // boundary matrices of this chunk
    __shared__ float sK[C1][16];   // K per segment
    __shared__ float sLf[16];
    int t = threadIdx.x;
    size_t g = (size_t)blockIdx.x * 256 + t;

    float e[16];
    load16(E + g * 16, e);          // coalesced: 4x float4 per lane
    if ((t & 7) == 7) {             // this lane holds a boundary pose (p == 7)
        int s = t >> 3;
#pragma unroll
        for (int q = 0; q < 16; ++q) sB[s][q] = e[q];
    }
    if (t < 16) sLf[t] = lf_in[t];
    __syncthreads();

    if (t < 4) {                    // row-parallel sequential chain, 32 steps
        const float* cp = chunkPrefix + (size_t)blockIdx.x * 16 + t * 4;
        float row0 = cp[0], row1 = cp[1], row2 = cp[2], row3 = cp[3];
        for (int k = 0; k < C1; ++k) {
            sK[k][t*4+0] = row0; sK[k][t*4+1] = row1;
            sK[k][t*4+2] = row2; sK[k][t*4+3] = row3;
            float n0, n1, n2, n3;
            n0 = fmaf(row3, sB[k][12], fmaf(row2, sB[k][8], fmaf(row1, sB[k][4], row0*sB[k][0])));
            n1 = fmaf(row3, sB[k][13], fmaf(row2, sB[k][9], fmaf(row1, sB[k][5], row0*sB[k][1])));
            n2 = fmaf(row3, sB[k][14], fmaf(row2, sB[k][10], fmaf(row1, sB[k][6], row0*sB[k][2])));
            n3 = fmaf(row3, sB[k][15], fmaf(row2, sB[k][11], fmaf(row1, sB[k][7], row0*sB[k][3])));
            row0 = n0; row1 = n1; row2 = n2; row3 = n3;
        }
    }
    __syncthreads();

    int s = t >> 3;
    float K[16];
#pragma unroll
    for (int q = 0; q < 16; ++q) K[q] = sK[s][q];
    float wf[16];
    mm4(K, e, wf);
    store16_nt(out + g * 16, wf);

    float lf[16];
#pragma unroll
    for (int q = 0; q < 16; ++q) lf[q] = sLf[q];
    float lfp[16];
    mm4(lf, wf, lfp);
    store16_nt(out + (size_t)B_POSES * 16 + g * 16, lfp);
}

extern "C" void kernel_launch(void* const* d_in, const int* in_sizes, int n_in,
                              void* d_out, int out_size, void* d_ws, size_t ws_size,
                              hipStream_t stream) {
    const float* E  = (const float*)d_in[0];
    const float* kf = (const float*)d_in[1];
    float* out = (float*)d_out;
    float* ws  = (float*)d_ws;
    float* chunkProd   = ws;                        // NCHUNK*16 floats
    float* chunkPrefix = ws + (size_t)NCHUNK * 16;  // NCHUNK*16 floats
    float* lf          = ws + (size_t)2 * NCHUNK * 16; // 16 floats

    k1_chunkprod<<<(NCHUNK * 4) / 256, 256, 0, stream>>>(E, chunkProd);
    k2_scan<<<1, 256, 0, stream>>>(kf, chunkProd, chunkPrefix, lf);
    k3_poses<<<B_POSES / 256, 256, 0, stream>>>(E, chunkPrefix, lf, out);
}

// Round 9
// 251.486 us; speedup vs baseline: 1.4070x; 1.4070x over previous
//
#include <hip/hip_runtime.h>

// Problem constants (fixed by the reference setup).
#define B_POSES  1048576
#define PERIOD   8
#define SEGS     (B_POSES / PERIOD)   // 131072 segments
#define C1       32                   // segments per chunk
#define NCHUNK   (SEGS / C1)          // 4096 chunks
#define SUP      16                   // chunks per super
#define NSUPER   (NCHUNK / SUP)       // 256 supers
#define HYP      16                   // supers per hyper
#define NHYPER   (NSUPER / HYP)       // 16 hypers

typedef float vfloat4 __attribute__((ext_vector_type(4)));

// c = a @ b, row-major 4x4. c must not alias a/b.
__device__ __forceinline__ void mm4(const float* __restrict__ a,
                                    const float* __restrict__ b,
                                    float* __restrict__ c) {
#pragma unroll
    for (int i = 0; i < 4; ++i) {
#pragma unroll
        for (int j = 0; j < 4; ++j) {
            float s = a[i*4+0] * b[0*4+j];
            s = fmaf(a[i*4+1], b[1*4+j], s);
            s = fmaf(a[i*4+2], b[2*4+j], s);
            c[i*4+j] = fmaf(a[i*4+3], b[3*4+j], s);
        }
    }
}

__device__ __forceinline__ void load16(const float* __restrict__ p, float* __restrict__ d) {
    const vfloat4* v = reinterpret_cast<const vfloat4*>(p);
    vfloat4 v0 = v[0], v1 = v[1], v2 = v[2], v3 = v[3];
    d[0]=v0.x; d[1]=v0.y; d[2]=v0.z; d[3]=v0.w;
    d[4]=v1.x; d[5]=v1.y; d[6]=v1.z; d[7]=v1.w;
    d[8]=v2.x; d[9]=v2.y; d[10]=v2.z; d[11]=v2.w;
    d[12]=v3.x; d[13]=v3.y; d[14]=v3.z; d[15]=v3.w;
}

// Plain L2-combining stores. NOTE (R6 post-mortem): __builtin_nontemporal_store
// here was a 5x k3 regression — nt bypasses L2 write-combining on gfx950 and
// inflated HBM WRITE_SIZE 134->338 MB. Keep plain stores.
__device__ __forceinline__ void store16(float* __restrict__ p, const float* __restrict__ s) {
    vfloat4* v = reinterpret_cast<vfloat4*>(p);
    v[0] = (vfloat4){s[0], s[1], s[2], s[3]};
    v[1] = (vfloat4){s[4], s[5], s[6], s[7]};
    v[2] = (vfloat4){s[8], s[9], s[10], s[11]};
    v[3] = (vfloat4){s[12], s[13], s[14], s[15]};
}

// K1: chunkProd[c] = boundary[c*C1] @ ... @ boundary[c*C1+C1-1]
// Quad-row parallel: 4 lanes per chunk, one output row each. Each lane reads
// the full boundary matrix (quad lanes share the 64B cache line), updates only
// its row: row_new = row @ B. Same association order as a serial chain.
__global__ __launch_bounds__(256)
void k1_chunkprod(const float* __restrict__ E, float* __restrict__ chunkProd) {
    int tid = blockIdx.x * 256 + threadIdx.x;   // grid = NCHUNK*4 threads
    int c = tid >> 2;
    int r = tid & 3;
    const float* base = E + ((size_t)c * C1 * PERIOD + (PERIOD - 1)) * 16;
    vfloat4 rv = *reinterpret_cast<const vfloat4*>(base + r * 4);
    float row0 = rv.x, row1 = rv.y, row2 = rv.z, row3 = rv.w;
    float bm[16];
#pragma unroll 4
    for (int k = 1; k < C1; ++k) {
        load16(base + (size_t)k * PERIOD * 16, bm);
        float n0 = fmaf(row3, bm[12], fmaf(row2, bm[8],  fmaf(row1, bm[4], row0*bm[0])));
        float n1 = fmaf(row3, bm[13], fmaf(row2, bm[9],  fmaf(row1, bm[5], row0*bm[1])));
        float n2 = fmaf(row3, bm[14], fmaf(row2, bm[10], fmaf(row1, bm[6], row0*bm[2])));
        float n3 = fmaf(row3, bm[15], fmaf(row2, bm[11], fmaf(row1, bm[7], row0*bm[3])));
        row0 = n0; row1 = n1; row2 = n2; row3 = n3;
    }
    *reinterpret_cast<vfloat4*>(chunkProd + (size_t)c * 16 + r * 4) =
        (vfloat4){row0, row1, row2, row3};
}

// K2: hierarchical exclusive scan over the 4096 chunk products, kf0 folded in
// on the left. chunkPrefix[c] = kf0 @ prod(chunkProd[0..c-1]). Also emits lf.
__global__ __launch_bounds__(256)
void k2_scan(const float* __restrict__ kf, const float* __restrict__ chunkProd,
             float* __restrict__ chunkPrefix, float* __restrict__ lf_out) {
    __shared__ float sSup[NSUPER][16];      // super products
    __shared__ float sSupPref[NSUPER][16];  // kf0-folded prefix per super
    __shared__ float sHyp[NHYPER][16];
    __shared__ float sHypPref[NHYPER][16];
    int t = threadIdx.x;
    float run[16], bm[16], tmp[16];

    // Stage A: super products (all 256 threads, chain of 16)
    {
        const float* p = chunkProd + (size_t)t * SUP * 16;
        load16(p, run);
#pragma unroll 4
        for (int k = 1; k < SUP; ++k) {
            load16(p + (size_t)k * 16, bm);
            mm4(run, bm, tmp);
#pragma unroll
            for (int q = 0; q < 16; ++q) run[q] = tmp[q];
        }
#pragma unroll
        for (int q = 0; q < 16; ++q) sSup[t][q] = run[q];
    }
    __syncthreads();

    // Stage B1: hyper products (16 threads, chain of 16)
    if (t < NHYPER) {
#pragma unroll
        for (int q = 0; q < 16; ++q) run[q] = sSup[t*HYP][q];
        for (int k = 1; k < HYP; ++k) {
            mm4(run, sSup[t*HYP + k], tmp);
#pragma unroll
            for (int q = 0; q < 16; ++q) run[q] = tmp[q];
        }
#pragma unroll
        for (int q = 0; q < 16; ++q) sHyp[t][q] = run[q];
    }
    __syncthreads();

    // Stage B2: serial scan over 16 hypers (thread 0), kf0 at the left; and lf.
    if (t == 0) {
        load16(kf, run);
        for (int h = 0; h < NHYPER; ++h) {
#pragma unroll
            for (int q = 0; q < 16; ++q) sHypPref[h][q] = run[q];
            mm4(run, sHyp[h], tmp);
#pragma unroll
            for (int q = 0; q < 16; ++q) run[q] = tmp[q];
        }
        // lf = [[R^T, -R^T t],[kf0 row 3]]
        float lf[16];
#pragma unroll
        for (int i = 0; i < 3; ++i)
#pragma unroll
            for (int j = 0; j < 3; ++j)
                lf[i*4+j] = kf[j*4+i];
#pragma unroll
        for (int i = 0; i < 3; ++i)
            lf[i*4+3] = -(kf[0*4+i]*kf[0*4+3] + kf[1*4+i]*kf[1*4+3] + kf[2*4+i]*kf[2*4+3]);
        lf[12] = kf[12]; lf[13] = kf[13]; lf[14] = kf[14]; lf[15] = kf[15];
        store16(lf_out, lf);
    }
    __syncthreads();

    // Stage B3: prefix within each hyper (16 threads, chain of 16)
    if (t < NHYPER) {
#pragma unroll
        for (int q = 0; q < 16; ++q) run[q] = sHypPref[t][q];
        for (int k = 0; k < HYP; ++k) {
            int s = t*HYP + k;
#pragma unroll
            for (int q = 0; q < 16; ++q) sSupPref[s][q] = run[q];
            mm4(run, sSup[s], tmp);
#pragma unroll
            for (int q = 0; q < 16; ++q) run[q] = tmp[q];
        }
    }
    __syncthreads();

    // Stage C: prefix within each super (256 threads, chain of 16), to global ws
    {
#pragma unroll
        for (int q = 0; q < 16; ++q) run[q] = sSupPref[t][q];
        for (int k = 0; k < SUP; ++k) {
            int c = t*SUP + k;
            store16(chunkPrefix + (size_t)c * 16, run);
            load16(chunkProd + (size_t)c * 16, bm);
            mm4(run, bm, tmp);
#pragma unroll
            for (int q = 0; q < 16; ++q) run[q] = tmp[q];
        }
    }
}

// K3: one block per chunk (32 segments * 8 poses = 256 threads).
// Lanes 0-3 extend the chunk prefix across the 32 segments (row-parallel,
// no cross-thread deps), then every thread computes wf and lf_poses.
__global__ __launch_bounds__(256)
void k3_poses(const float* __restrict__ E, const float* __restrict__ chunkPrefix,
              const float* __restrict__ lf_in, float* __restrict__ out) {
    __shared__ float sB[C1][16];   // boundary matrices of this chunk
    __shared__ float sK[C1][16];   // K per segment
    __shared__ float sLf[16];
    int t = threadIdx.x;
    size_t g = (size_t)blockIdx.x * 256 + t;

    float e[16];
    load16(E + g * 16, e);          // coalesced: 4x float4 per lane
    if ((t & 7) == 7) {             // this lane holds a boundary pose (p == 7)
        int s = t >> 3;
#pragma unroll
        for (int q = 0; q < 16; ++q) sB[s][q] = e[q];
    }
    if (t < 16) sLf[t] = lf_in[t];
    __syncthreads();

    if (t < 4) {                    // row-parallel sequential chain, 32 steps
        const float* cp = chunkPrefix + (size_t)blockIdx.x * 16 + t * 4;
        float row0 = cp[0], row1 = cp[1], row2 = cp[2], row3 = cp[3];
        for (int k = 0; k < C1; ++k) {
            sK[k][t*4+0] = row0; sK[k][t*4+1] = row1;
            sK[k][t*4+2] = row2; sK[k][t*4+3] = row3;
            float n0, n1, n2, n3;
            n0 = fmaf(row3, sB[k][12], fmaf(row2, sB[k][8], fmaf(row1, sB[k][4], row0*sB[k][0])));
            n1 = fmaf(row3, sB[k][13], fmaf(row2, sB[k][9], fmaf(row1, sB[k][5], row0*sB[k][1])));
            n2 = fmaf(row3, sB[k][14], fmaf(row2, sB[k][10], fmaf(row1, sB[k][6], row0*sB[k][2])));
            n3 = fmaf(row3, sB[k][15], fmaf(row2, sB[k][11], fmaf(row1, sB[k][7], row0*sB[k][3])));
            row0 = n0; row1 = n1; row2 = n2; row3 = n3;
        }
    }
    __syncthreads();

    int s = t >> 3;
    float K[16];
#pragma unroll
    for (int q = 0; q < 16; ++q) K[q] = sK[s][q];
    float wf[16];
    mm4(K, e, wf);
    store16(out + g * 16, wf);

    float lf[16];
#pragma unroll
    for (int q = 0; q < 16; ++q) lf[q] = sLf[q];
    float lfp[16];
    mm4(lf, wf, lfp);
    store16(out + (size_t)B_POSES * 16 + g * 16, lfp);
}

extern "C" void kernel_launch(void* const* d_in, const int* in_sizes, int n_in,
                              void* d_out, int out_size, void* d_ws, size_t ws_size,
                              hipStream_t stream) {
    const float* E  = (const float*)d_in[0];
    const float* kf = (const float*)d_in[1];
    float* out = (float*)d_out;
    float* ws  = (float*)d_ws;
    float* chunkProd   = ws;                        // NCHUNK*16 floats
    float* chunkPrefix = ws + (size_t)NCHUNK * 16;  // NCHUNK*16 floats
    float* lf          = ws + (size_t)2 * NCHUNK * 16; // 16 floats

    k1_chunkprod<<<(NCHUNK * 4) / 256, 256, 0, stream>>>(E, chunkProd);
    k2_scan<<<1, 256, 0, stream>>>(kf, chunkProd, chunkPrefix, lf);
    k3_poses<<<B_POSES / 256, 256, 0, stream>>>(E, chunkPrefix, lf, out);
}